// Round 2
// baseline (25648.151 us; speedup 1.0000x reference)
//
#include <hip/hip_runtime.h>

// ---------------------------------------------------------------------------
// RGCN (basis decomposition), 2 layers. N=50000, E=1e6, H=128, O=64, R=16.
// Round 2: kill the global-atomic storm (round 1: 37.5 GB HBM traffic, VALU
// 5%). Edges counting-sorted by bin=(dst/DSTBLK)*16+etype; one block owns
// DSTBLK=100 destination nodes, accumulates messages in an LDS accumulator
// (ds_add_f32), writes each node row exactly once. GEMM core = round-1 4x4
// microtile (known correct). xs/ws rows padded (132/68) vs round-1 bank
// conflicts.
// ---------------------------------------------------------------------------

#define RELS 16
#define HDIM 128
#define DSTBLK 100
#define MAXBINS 8192

__global__ void compute_w(const float* __restrict__ comp, const float* __restrict__ V,
                          float* __restrict__ W, int IO) {
  int idx = blockIdx.x * blockDim.x + threadIdx.x;
  if (idx >= RELS * IO) return;
  int r = idx / IO, p = idx - r * IO;
  float s = 0.f;
#pragma unroll
  for (int b = 0; b < RELS; b++) s = fmaf(comp[r * RELS + b], V[b * IO + p], s);
  W[idx] = s;
}

__global__ void hist_bins(const int* __restrict__ dst, const int* __restrict__ etype,
                          int n, int nbins, int* __restrict__ counts) {
  __shared__ int lh[MAXBINS];
  for (int j = threadIdx.x; j < nbins; j += blockDim.x) lh[j] = 0;
  __syncthreads();
  for (int i = blockIdx.x * blockDim.x + threadIdx.x; i < n; i += gridDim.x * blockDim.x) {
    int b = (dst[i] / DSTBLK) * RELS + etype[i];
    atomicAdd(&lh[b], 1);
  }
  __syncthreads();
  for (int j = threadIdx.x; j < nbins; j += blockDim.x) {
    int c = lh[j];
    if (c) atomicAdd(&counts[j], c);
  }
}

// Exclusive scan of per-bin counts, each padded up to a multiple of 64.
// Single block of 256 threads; writes offsets[0..nbins].
__global__ void scan_offsets(const int* __restrict__ counts, int* __restrict__ offsets,
                             int nbins) {
  __shared__ int csum[257];
  const int t = threadIdx.x;
  const int CH = (nbins + 255) / 256;
  int lo = t * CH, hi = min(lo + CH, nbins);
  int s = 0;
  for (int i = lo; i < hi; i++) s += (counts[i] + 63) & ~63;
  csum[t + 1] = s;
  if (t == 0) csum[0] = 0;
  __syncthreads();
  if (t == 0)
    for (int i = 1; i <= 256; i++) csum[i] += csum[i - 1];
  __syncthreads();
  int run = csum[t];
  for (int i = lo; i < hi; i++) {
    offsets[i] = run;
    run += (counts[i] + 63) & ~63;
  }
  if (lo < hi && hi == nbins) offsets[nbins] = run;
}

__global__ void scatter_bins(const int* __restrict__ src, const int* __restrict__ dst,
                             const int* __restrict__ etype, const float* __restrict__ norm,
                             int n, const int* __restrict__ offsets, int* __restrict__ cursor,
                             int* __restrict__ sb, int* __restrict__ db, float* __restrict__ nb) {
  for (int i = blockIdx.x * blockDim.x + threadIdx.x; i < n; i += gridDim.x * blockDim.x) {
    int d = dst[i];
    int b = (d / DSTBLK) * RELS + etype[i];
    int p = offsets[b] + atomicAdd(&cursor[b], 1);
    sb[p] = src[i];
    db[p] = d;
    nb[p] = norm[i];
  }
}

// One block owns DSTBLK consecutive destination nodes. Walk the block's 16
// relation bins; per 64-edge tile: gather x[src] rows into LDS, tile-GEMM vs
// LDS-staged W_r chunk (4x4 microtile per thread over 64 edges x 64 out),
// scale by norm, ds_add_f32 into the LDS accumulator. Epilogue: +bias, one
// coalesced write per node row. No global atomics anywhere.
template <int OUT, bool RELU_IN>
__launch_bounds__(256, 1)
__global__ void rgcn_layer(const float* __restrict__ X, const float* __restrict__ W,
                           const int* __restrict__ sb, const int* __restrict__ db,
                           const float* __restrict__ nb, const int* __restrict__ offsets,
                           const float* __restrict__ bias, float* __restrict__ Hout,
                           int nNodes) {
  __shared__ __align__(16) float xs[64][132];   // +4 pad: 4-way -> free on a-reads
  __shared__ __align__(16) float ws[HDIM][68];  // +4 pad: 8-way -> ~2-way on stage writes
  __shared__ float acc[DSTBLK * OUT];
  const int t = threadIdx.x;
  const int blk = blockIdx.x;
  const int nodeBase = blk * DSTBLK;

  for (int i = t; i < DSTBLK * OUT; i += 256) acc[i] = 0.f;

  const int eg = t >> 4, og = t & 15;

  for (int r = 0; r < RELS; r++) {
    const int bin = blk * RELS + r;
    const int start = offsets[bin];
    const int end = offsets[bin + 1];
    const float* Wr = W + (size_t)r * HDIM * OUT;
    for (int base = start; base < end; base += 64) {
      __syncthreads();  // previous tile's consumers (xs, ws) done; acc atomics drained
      // gather 64 source rows, float4-coalesced; pad slots (sb==-1) load zeros
#pragma unroll
      for (int c = 0; c < 8; c++) {
        int idx = c * 256 + t;
        int e = idx >> 5, k4 = idx & 31;
        int s = sb[base + e];
        float4 v = make_float4(0.f, 0.f, 0.f, 0.f);
        if (s >= 0) v = ((const float4*)(X + (size_t)s * HDIM))[k4];
        if (RELU_IN) {
          v.x = fmaxf(v.x, 0.f); v.y = fmaxf(v.y, 0.f);
          v.z = fmaxf(v.z, 0.f); v.w = fmaxf(v.w, 0.f);
        }
        *(float4*)&xs[e][k4 * 4] = v;
      }

      // per-thread edge metadata (4 edges of this tile)
      int dl[4];
      float nm[4];
#pragma unroll
      for (int ii = 0; ii < 4; ii++) {
        int ei = base + eg * 4 + ii;
        int d = db[ei];
        dl[ii] = (d >= 0) ? (d - nodeBase) : -1;
        nm[ii] = nb[ei];
      }

#pragma unroll
      for (int oc = 0; oc < OUT / 64; oc++) {
        if (oc > 0) __syncthreads();  // oc-1's ws consumers done
        // stage W chunk [128][64]
#pragma unroll
        for (int c = 0; c < 8; c++) {
          int idx = c * 256 + t;
          int k = idx >> 4, o4 = idx & 15;
          *(float4*)&ws[k][o4 * 4] = ((const float4*)(Wr + (size_t)k * OUT + oc * 64))[o4];
        }
        __syncthreads();  // xs + ws visible

        float accl[4][4] = {};
#pragma unroll
        for (int k = 0; k < HDIM; k += 4) {
          float4 a[4], b[4];
#pragma unroll
          for (int ii = 0; ii < 4; ii++) a[ii] = *(const float4*)&xs[eg * 4 + ii][k];
#pragma unroll
          for (int kk = 0; kk < 4; kk++) b[kk] = *(const float4*)&ws[k + kk][og * 4];
#pragma unroll
          for (int ii = 0; ii < 4; ii++) {
            const float av[4] = {a[ii].x, a[ii].y, a[ii].z, a[ii].w};
#pragma unroll
            for (int kk = 0; kk < 4; kk++) {
              accl[ii][0] = fmaf(av[kk], b[kk].x, accl[ii][0]);
              accl[ii][1] = fmaf(av[kk], b[kk].y, accl[ii][1]);
              accl[ii][2] = fmaf(av[kk], b[kk].z, accl[ii][2]);
              accl[ii][3] = fmaf(av[kk], b[kk].w, accl[ii][3]);
            }
          }
        }

        // scale by norm, accumulate into LDS accumulator (ds_add_f32)
#pragma unroll
        for (int ii = 0; ii < 4; ii++) {
          if (dl[ii] >= 0) {
            float* ap = &acc[dl[ii] * OUT + oc * 64 + og * 4];
            unsafeAtomicAdd(ap + 0, accl[ii][0] * nm[ii]);
            unsafeAtomicAdd(ap + 1, accl[ii][1] * nm[ii]);
            unsafeAtomicAdd(ap + 2, accl[ii][2] * nm[ii]);
            unsafeAtomicAdd(ap + 3, accl[ii][3] * nm[ii]);
          }
        }
      }
    }
  }
  __syncthreads();
  // epilogue: one non-atomic coalesced write per owned node row, +bias
  for (int i = t; i < DSTBLK * OUT / 4; i += 256) {
    int ld = i / (OUT / 4);
    int o4 = i - ld * (OUT / 4);
    int node = nodeBase + ld;
    if (node < nNodes) {
      float4 v = *(float4*)&acc[ld * OUT + o4 * 4];
      float4 bb = ((const float4*)bias)[o4];
      v.x += bb.x; v.y += bb.y; v.z += bb.z; v.w += bb.w;
      ((float4*)(Hout + (size_t)node * OUT))[o4] = v;
    }
  }
}

extern "C" void kernel_launch(void* const* d_in, const int* in_sizes, int n_in,
                              void* d_out, int out_size, void* d_ws, size_t ws_size,
                              hipStream_t stream) {
  const int*   src   = (const int*)d_in[1];
  const int*   dst   = (const int*)d_in[2];
  const int*   etype = (const int*)d_in[3];
  const float* norm  = (const float*)d_in[4];
  const float* emb   = (const float*)d_in[5];
  const float* V1    = (const float*)d_in[6];
  const float* comp1 = (const float*)d_in[7];
  const float* bias1 = (const float*)d_in[8];
  const float* V2    = (const float*)d_in[9];
  const float* comp2 = (const float*)d_in[10];
  const float* bias2 = (const float*)d_in[11];
  float* out = (float*)d_out;

  const int N = in_sizes[0];  // 50000
  const int E = in_sizes[1];  // 1000000
  const int H = 128, O = 64;
  const int NB = (N + DSTBLK - 1) / DSTBLK;  // 500
  const int NBINS = NB * RELS;               // 8000
  const int EPAD_MAX = E + NBINS * 64;

  char* ws = (char*)d_ws;
  size_t off = 0;
  auto alloc = [&](size_t bytes) -> void* {
    void* p = ws + off;
    off += (bytes + 255) & ~(size_t)255;
    return p;
  };
  float* W1 = (float*)alloc(sizeof(float) * RELS * H * H);
  float* W2 = (float*)alloc(sizeof(float) * RELS * H * O);
  float* h1 = (float*)alloc(sizeof(float) * (size_t)N * H);
  int*   sb = (int*)alloc(sizeof(int) * EPAD_MAX);
  int*   db = (int*)alloc(sizeof(int) * EPAD_MAX);
  float* nb = (float*)alloc(sizeof(float) * EPAD_MAX);
  int* counts  = (int*)alloc(sizeof(int) * NBINS);
  int* cursor  = (int*)alloc(sizeof(int) * NBINS);
  int* offsets = (int*)alloc(sizeof(int) * (NBINS + 1));

  hipMemsetAsync(counts, 0, sizeof(int) * NBINS, stream);
  hipMemsetAsync(cursor, 0, sizeof(int) * NBINS, stream);
  hipMemsetAsync(sb, 0xFF, sizeof(int) * EPAD_MAX, stream);
  hipMemsetAsync(db, 0xFF, sizeof(int) * EPAD_MAX, stream);

  compute_w<<<(RELS * H * H + 255) / 256, 256, 0, stream>>>(comp1, V1, W1, H * H);
  compute_w<<<(RELS * H * O + 255) / 256, 256, 0, stream>>>(comp2, V2, W2, H * O);
  hist_bins<<<512, 256, 0, stream>>>(dst, etype, E, NBINS, counts);
  scan_offsets<<<1, 256, 0, stream>>>(counts, offsets, NBINS);
  scatter_bins<<<512, 256, 0, stream>>>(src, dst, etype, norm, E, offsets, cursor, sb, db, nb);

  rgcn_layer<128, false><<<NB, 256, 0, stream>>>(emb, W1, sb, db, nb, offsets, bias1, h1, N);
  rgcn_layer<64, true><<<NB, 256, 0, stream>>>(h1, W2, sb, db, nb, offsets, bias2, out, N);
}

// Round 3
// 1421.512 us; speedup vs baseline: 18.0429x; 18.0429x over previous
//
#include <hip/hip_runtime.h>

// ---------------------------------------------------------------------------
// RGCN (basis decomposition), 2 layers. N=50000, E=1e6, H=128, O=64, R=16.
// Round 3: rounds 1-2 were scratch-spill bound (VGPR_Count=256 cap, ~20 GB
// symmetric FETCH/WRITE, VALUBusy <6%). Replace fp32 VALU GEMM with bf16
// MFMA 16x16x32 (verified layouts: A[m=lane&15][k=quad*8+j], B from B^T rows,
// D[row=quad*4+reg][col=lane&15]). W kept in registers per bin; LDS = xs tile
// + fp32 node accumulator (69 KB -> 2 blocks/CU). Bins padded to 16 edges
// (+6% vs +26%). bf16 gathers (emb pre-converted, h1 stored bf16+ReLU).
// ---------------------------------------------------------------------------

typedef short bf16x8 __attribute__((ext_vector_type(8)));
typedef float f32x4 __attribute__((ext_vector_type(4)));

#define RELS 16
#define HDIM 128
#define DSTBLK 100
#define MAXBINS 8192

__device__ inline unsigned short f2bf(float f) {
  unsigned int u = __float_as_uint(f);
  unsigned int r = u + 0x7FFFu + ((u >> 16) & 1u);
  return (unsigned short)(r >> 16);
}

// emb fp32 -> bf16, 8 elems/thread
__global__ void cvt_bf16(const float* __restrict__ in, unsigned short* __restrict__ out, int n8) {
  int i = blockIdx.x * blockDim.x + threadIdx.x;
  if (i >= n8) return;
  float4 a = ((const float4*)in)[i * 2];
  float4 b = ((const float4*)in)[i * 2 + 1];
  uint4 o;
  o.x = (unsigned)f2bf(a.x) | ((unsigned)f2bf(a.y) << 16);
  o.y = (unsigned)f2bf(a.z) | ((unsigned)f2bf(a.w) << 16);
  o.z = (unsigned)f2bf(b.x) | ((unsigned)f2bf(b.y) << 16);
  o.w = (unsigned)f2bf(b.z) | ((unsigned)f2bf(b.w) << 16);
  ((uint4*)out)[i] = o;
}

// Wt[r][o][k] (bf16, transposed) = sum_b comp[r,b] * V[b,k,o]
__global__ void compute_w(const float* __restrict__ comp, const float* __restrict__ V,
                          unsigned short* __restrict__ Wt, int IO) {
  int idx = blockIdx.x * blockDim.x + threadIdx.x;
  if (idx >= RELS * IO * HDIM) return;
  int k = idx & (HDIM - 1);
  int o = (idx >> 7) % IO;
  int r = idx / (IO * HDIM);
  float s = 0.f;
#pragma unroll
  for (int b = 0; b < RELS; b++) s = fmaf(comp[r * RELS + b], V[(size_t)b * HDIM * IO + (size_t)k * IO + o], s);
  Wt[idx] = f2bf(s);
}

__global__ void hist_bins(const int* __restrict__ dst, const int* __restrict__ etype,
                          int n, int nbins, int* __restrict__ counts) {
  __shared__ int lh[MAXBINS];
  for (int j = threadIdx.x; j < nbins; j += blockDim.x) lh[j] = 0;
  __syncthreads();
  for (int i = blockIdx.x * blockDim.x + threadIdx.x; i < n; i += gridDim.x * blockDim.x)
    atomicAdd(&lh[(dst[i] / DSTBLK) * RELS + etype[i]], 1);
  __syncthreads();
  for (int j = threadIdx.x; j < nbins; j += blockDim.x) {
    int c = lh[j];
    if (c) atomicAdd(&counts[j], c);
  }
}

// exclusive scan of counts padded to multiples of 16
__global__ void scan_offsets(const int* __restrict__ counts, int* __restrict__ offsets, int nbins) {
  __shared__ int csum[257];
  const int t = threadIdx.x;
  const int CH = (nbins + 255) / 256;
  int lo = t * CH, hi = min(lo + CH, nbins);
  int s = 0;
  for (int i = lo; i < hi; i++) s += (counts[i] + 15) & ~15;
  csum[t + 1] = s;
  if (t == 0) csum[0] = 0;
  __syncthreads();
  if (t == 0)
    for (int i = 1; i <= 256; i++) csum[i] += csum[i - 1];
  __syncthreads();
  int run = csum[t];
  for (int i = lo; i < hi; i++) {
    offsets[i] = run;
    run += (counts[i] + 15) & ~15;
  }
  if (lo < hi && hi == nbins) offsets[nbins] = run;
}

// ebuf[p] = {src, dst, norm_bits, 0}; pad slots stay 0xFF (src=dst=-1)
__global__ void scatter_bins(const int* __restrict__ src, const int* __restrict__ dst,
                             const int* __restrict__ etype, const float* __restrict__ norm,
                             int n, const int* __restrict__ offsets, int* __restrict__ cursor,
                             int4* __restrict__ ebuf) {
  for (int i = blockIdx.x * blockDim.x + threadIdx.x; i < n; i += gridDim.x * blockDim.x) {
    int d = dst[i];
    int b = (d / DSTBLK) * RELS + etype[i];
    int p = offsets[b] + atomicAdd(&cursor[b], 1);
    ebuf[p] = make_int4(src[i], d, __float_as_int(norm[i]), 0);
  }
}

// One block owns DSTBLK nodes; walks its 16 relation bins. Per 64-edge chunk:
// gather bf16 src rows into xs, MFMA vs register-resident W frags, scale by
// norm, ds_add_f32 into LDS accumulator. Epilogue writes each node once.
// Wave w: edges [(w>>1)*32, +32), out columns [(w&1)*OUT/2, +OUT/2).
template <int OUT, bool RELU_BF16_OUT>
__launch_bounds__(256, 2)
__global__ void rgcn_layer(const unsigned short* __restrict__ Xb,  // [N][128] bf16
                           const unsigned short* __restrict__ Wt,  // [R][OUT][128] bf16
                           const int4* __restrict__ ebuf,
                           const int* __restrict__ offsets,        // bin = blk*16+r
                           const float* __restrict__ bias,
                           void* __restrict__ Hout, int nNodes) {
  constexpr int NT = OUT / 32;  // n-tiles per wave (half of OUT, 16 wide each)
  __shared__ __align__(16) unsigned short xs[64][136];  // 136: 16B-aligned rows, even banks
  __shared__ float acc[DSTBLK * (OUT + 1)];             // +1: break bank alignment
  const int t = threadIdx.x;
  const int w = t >> 6;
  const int lane = t & 63;
  const int quad = lane >> 4;
  const int l16 = lane & 15;
  const int nodeBase = blockIdx.x * DSTBLK;
  const int eBaseW = (w >> 1) * 32;
  const int n0w = (w & 1) * (OUT / 2);

  for (int i = t; i < DSTBLK * (OUT + 1); i += 256) acc[i] = 0.f;

  for (int r = 0; r < RELS; r++) {
    const int bin = blockIdx.x * RELS + r;
    const int start = offsets[bin];
    const int end = offsets[bin + 1];
    if (start == end) continue;

    // W fragments for this relation, register-resident for the whole bin
    const unsigned short* Wr = Wt + (size_t)r * OUT * HDIM;
    bf16x8 bfr[4][NT];
#pragma unroll
    for (int ks = 0; ks < 4; ks++)
#pragma unroll
      for (int nt = 0; nt < NT; nt++)
        bfr[ks][nt] = *(const bf16x8*)(Wr + (size_t)(n0w + nt * 16 + l16) * HDIM + ks * 32 + quad * 8);

    for (int base = start; base < end; base += 64) {
      const int nrows = min(64, end - base);  // multiple of 16
      __syncthreads();  // previous chunk's xs readers done
#pragma unroll
      for (int i = 0; i < 4; i++) {
        int idx = i * 256 + t;
        int row = idx >> 4, k8 = idx & 15;
        if (row < nrows) {
          int s = ebuf[base + row].x;
          uint4 v = make_uint4(0u, 0u, 0u, 0u);
          if (s >= 0) v = *(const uint4*)(Xb + (size_t)s * HDIM + k8 * 8);
          *(uint4*)&xs[row][k8 * 8] = v;
        }
      }
      __syncthreads();  // xs visible

      const bool act1 = (eBaseW + 16) < nrows;
      if (eBaseW < nrows) {
        f32x4 dacc[2][NT] = {};
#pragma unroll
        for (int ks = 0; ks < 4; ks++) {
          bf16x8 a0 = *(const bf16x8*)&xs[eBaseW + l16][ks * 32 + quad * 8];
          bf16x8 a1 = act1 ? *(const bf16x8*)&xs[eBaseW + 16 + l16][ks * 32 + quad * 8] : bf16x8{};
#pragma unroll
          for (int nt = 0; nt < NT; nt++) {
            dacc[0][nt] = __builtin_amdgcn_mfma_f32_16x16x32_bf16(a0, bfr[ks][nt], dacc[0][nt], 0, 0, 0);
            if (act1)
              dacc[1][nt] = __builtin_amdgcn_mfma_f32_16x16x32_bf16(a1, bfr[ks][nt], dacc[1][nt], 0, 0, 0);
          }
        }
        // scale by norm, scatter into LDS accumulator
#pragma unroll
        for (int mt = 0; mt < 2; mt++) {
          if (mt == 1 && !act1) break;
          int eRow = base + eBaseW + mt * 16 + quad * 4;
#pragma unroll
          for (int reg = 0; reg < 4; reg++) {
            int4 md = ebuf[eRow + reg];
            if (md.y >= 0) {
              float nm = __int_as_float(md.z);
              float* ap = &acc[(md.y - nodeBase) * (OUT + 1) + n0w + l16];
#pragma unroll
              for (int nt = 0; nt < NT; nt++)
                unsafeAtomicAdd(ap + nt * 16, dacc[mt][nt][reg] * nm);
            }
          }
        }
      }
    }
  }
  __syncthreads();  // all atomics drained

  if constexpr (RELU_BF16_OUT) {
    unsigned short* Hb = (unsigned short*)Hout;
    for (int i = t; i < DSTBLK * OUT / 8; i += 256) {
      int ld = i / (OUT / 8), o8 = i % (OUT / 8);
      int node = nodeBase + ld;
      if (node < nNodes) {
        unsigned short h[8];
#pragma unroll
        for (int j = 0; j < 8; j++) {
          float v = acc[ld * (OUT + 1) + o8 * 8 + j] + bias[o8 * 8 + j];
          h[j] = f2bf(fmaxf(v, 0.f));
        }
        uint4 o;
        o.x = (unsigned)h[0] | ((unsigned)h[1] << 16);
        o.y = (unsigned)h[2] | ((unsigned)h[3] << 16);
        o.z = (unsigned)h[4] | ((unsigned)h[5] << 16);
        o.w = (unsigned)h[6] | ((unsigned)h[7] << 16);
        *(uint4*)(Hb + (size_t)node * OUT + o8 * 8) = o;
      }
    }
  } else {
    float* Hf = (float*)Hout;
    for (int i = t; i < DSTBLK * OUT / 4; i += 256) {
      int ld = i / (OUT / 4), o4 = i % (OUT / 4);
      int node = nodeBase + ld;
      if (node < nNodes) {
        float4 v;
        v.x = acc[ld * (OUT + 1) + o4 * 4 + 0] + bias[o4 * 4 + 0];
        v.y = acc[ld * (OUT + 1) + o4 * 4 + 1] + bias[o4 * 4 + 1];
        v.z = acc[ld * (OUT + 1) + o4 * 4 + 2] + bias[o4 * 4 + 2];
        v.w = acc[ld * (OUT + 1) + o4 * 4 + 3] + bias[o4 * 4 + 3];
        *(float4*)(Hf + (size_t)node * OUT + o4 * 4) = v;
      }
    }
  }
}

extern "C" void kernel_launch(void* const* d_in, const int* in_sizes, int n_in,
                              void* d_out, int out_size, void* d_ws, size_t ws_size,
                              hipStream_t stream) {
  const int*   src   = (const int*)d_in[1];
  const int*   dst   = (const int*)d_in[2];
  const int*   etype = (const int*)d_in[3];
  const float* norm  = (const float*)d_in[4];
  const float* emb   = (const float*)d_in[5];
  const float* V1    = (const float*)d_in[6];
  const float* comp1 = (const float*)d_in[7];
  const float* bias1 = (const float*)d_in[8];
  const float* V2    = (const float*)d_in[9];
  const float* comp2 = (const float*)d_in[10];
  const float* bias2 = (const float*)d_in[11];
  float* out = (float*)d_out;

  const int N = in_sizes[0];  // 50000
  const int E = in_sizes[1];  // 1000000
  const int H = 128, O = 64;
  const int NB = (N + DSTBLK - 1) / DSTBLK;  // 500
  const int NBINS = NB * RELS;               // 8000
  const int EPAD_MAX = E + NBINS * 16;

  char* ws = (char*)d_ws;
  size_t off = 0;
  auto alloc = [&](size_t bytes) -> void* {
    void* p = ws + off;
    off += (bytes + 255) & ~(size_t)255;
    return p;
  };
  unsigned short* W1t  = (unsigned short*)alloc(sizeof(short) * RELS * H * H);
  unsigned short* W2t  = (unsigned short*)alloc(sizeof(short) * RELS * O * H);
  unsigned short* embh = (unsigned short*)alloc(sizeof(short) * (size_t)N * H);
  unsigned short* h1b  = (unsigned short*)alloc(sizeof(short) * (size_t)N * H);
  int4* ebuf = (int4*)alloc(sizeof(int4) * EPAD_MAX);
  int* counts  = (int*)alloc(sizeof(int) * NBINS);
  int* cursor  = (int*)alloc(sizeof(int) * NBINS);
  int* offsets = (int*)alloc(sizeof(int) * (NBINS + 1));

  hipMemsetAsync(counts, 0, sizeof(int) * NBINS, stream);
  hipMemsetAsync(cursor, 0, sizeof(int) * NBINS, stream);
  hipMemsetAsync(ebuf, 0xFF, sizeof(int4) * EPAD_MAX, stream);

  cvt_bf16<<<((size_t)N * H / 8 + 255) / 256, 256, 0, stream>>>(emb, embh, N * H / 8);
  compute_w<<<(RELS * H * H + 255) / 256, 256, 0, stream>>>(comp1, V1, W1t, H);
  compute_w<<<(RELS * O * H + 255) / 256, 256, 0, stream>>>(comp2, V2, W2t, O);
  hist_bins<<<512, 256, 0, stream>>>(dst, etype, E, NBINS, counts);
  scan_offsets<<<1, 256, 0, stream>>>(counts, offsets, NBINS);
  scatter_bins<<<512, 256, 0, stream>>>(src, dst, etype, norm, E, offsets, cursor, ebuf);

  rgcn_layer<128, true><<<NB, 256, 0, stream>>>(embh, W1t, ebuf, offsets, bias1, (void*)h1b, N);
  rgcn_layer<64, false><<<NB, 256, 0, stream>>>(h1b, W2t, ebuf, offsets, bias2, (void*)out, N);
}

// Round 4
// 548.140 us; speedup vs baseline: 46.7912x; 2.5933x over previous
//
#include <hip/hip_runtime.h>

// ---------------------------------------------------------------------------
// RGCN (basis decomposition), 2 layers. N=50000, E=1e6, H=128, O=64, R=16.
// Round 4: round 3 was stall-bound on the per-element LDS atomic scatter
// (MfmaUtil 1.8%, VALUBusy 2.5%, 128M lane-atomics via unsafeAtomicAdd on a
// generic pointer). This round removes ALL atomics from the layer kernel:
// per 64-edge chunk, messages Y = xs @ W_r (MFMA #1, C-layout regs) are
// norm-scaled, bf16-converted, staged to LDS ys^T[col][edge]; an indicator
// matrix P[112x64] (bf16 1.0 at [dst_local][edge], duplicates in distinct
// columns -> no atomics) is built in LDS; then Pacc += P @ Y (MFMA #2) with
// Pacc register-resident per wave (disjoint col quarters) for the whole
// kernel. Epilogue writes each node exactly once. Entry-zero xs/ys so 0*stale
// never yields NaN. ebuf memset dropped (validity from real counts).
// ---------------------------------------------------------------------------

typedef short bf16x8 __attribute__((ext_vector_type(8)));
typedef float f32x4 __attribute__((ext_vector_type(4)));

#define RELS 16
#define HDIM 128
#define DSTBLK 100
#define MT_P 7  // ceil(DSTBLK/16) -> P has 112 rows

__device__ inline unsigned short f2bf(float f) {
  unsigned int u = __float_as_uint(f);
  unsigned int r = u + 0x7FFFu + ((u >> 16) & 1u);
  return (unsigned short)(r >> 16);
}

__global__ void cvt_bf16(const float* __restrict__ in, unsigned short* __restrict__ out, int n8) {
  int i = blockIdx.x * blockDim.x + threadIdx.x;
  if (i >= n8) return;
  float4 a = ((const float4*)in)[i * 2];
  float4 b = ((const float4*)in)[i * 2 + 1];
  uint4 o;
  o.x = (unsigned)f2bf(a.x) | ((unsigned)f2bf(a.y) << 16);
  o.y = (unsigned)f2bf(a.z) | ((unsigned)f2bf(a.w) << 16);
  o.z = (unsigned)f2bf(b.x) | ((unsigned)f2bf(b.y) << 16);
  o.w = (unsigned)f2bf(b.z) | ((unsigned)f2bf(b.w) << 16);
  ((uint4*)out)[i] = o;
}

// Wt[r][o][k] (bf16, transposed) = sum_b comp[r,b] * V[b,k,o]
__global__ void compute_w(const float* __restrict__ comp, const float* __restrict__ V,
                          unsigned short* __restrict__ Wt, int IO) {
  int idx = blockIdx.x * blockDim.x + threadIdx.x;
  if (idx >= RELS * IO * HDIM) return;
  int k = idx & (HDIM - 1);
  int o = (idx >> 7) % IO;
  int r = idx / (IO * HDIM);
  float s = 0.f;
#pragma unroll
  for (int b = 0; b < RELS; b++)
    s = fmaf(comp[r * RELS + b], V[(size_t)b * HDIM * IO + (size_t)k * IO + o], s);
  Wt[idx] = f2bf(s);
}

__global__ void hist_bins(const int* __restrict__ dst, const int* __restrict__ etype,
                          int n, int nbins, int* __restrict__ counts) {
  __shared__ int lh[8192];
  for (int j = threadIdx.x; j < nbins; j += blockDim.x) lh[j] = 0;
  __syncthreads();
  for (int i = blockIdx.x * blockDim.x + threadIdx.x; i < n; i += gridDim.x * blockDim.x)
    atomicAdd(&lh[(dst[i] / DSTBLK) * RELS + etype[i]], 1);
  __syncthreads();
  for (int j = threadIdx.x; j < nbins; j += blockDim.x) {
    int c = lh[j];
    if (c) atomicAdd(&counts[j], c);
  }
}

// exclusive scan of counts padded to multiples of 16
__global__ void scan_offsets(const int* __restrict__ counts, int* __restrict__ offsets, int nbins) {
  __shared__ int csum[257];
  const int t = threadIdx.x;
  const int CH = (nbins + 255) / 256;
  int lo = t * CH, hi = min(lo + CH, nbins);
  int s = 0;
  for (int i = lo; i < hi; i++) s += (counts[i] + 15) & ~15;
  csum[t + 1] = s;
  if (t == 0) csum[0] = 0;
  __syncthreads();
  if (t == 0)
    for (int i = 1; i <= 256; i++) csum[i] += csum[i - 1];
  __syncthreads();
  int run = csum[t];
  for (int i = lo; i < hi; i++) {
    offsets[i] = run;
    run += (counts[i] + 15) & ~15;
  }
  if (lo < hi && hi == nbins) offsets[nbins] = run;
}

// ebuf[p] = {src, dst, norm_bits, 0}; only real slots written (no memset)
__global__ void scatter_bins(const int* __restrict__ src, const int* __restrict__ dst,
                             const int* __restrict__ etype, const float* __restrict__ norm,
                             int n, const int* __restrict__ offsets, int* __restrict__ cursor,
                             int4* __restrict__ ebuf) {
  for (int i = blockIdx.x * blockDim.x + threadIdx.x; i < n; i += gridDim.x * blockDim.x) {
    int d = dst[i];
    int b = (d / DSTBLK) * RELS + etype[i];
    int p = offsets[b] + atomicAdd(&cursor[b], 1);
    ebuf[p] = make_int4(src[i], d, __float_as_int(norm[i]), 0);
  }
}

// One block owns DSTBLK nodes; walks its 16 relation bins in 64-edge chunks.
// Wave w owns output columns [w*OUT/4, +OUT/4). NT = OUT/64 n-tiles per wave.
template <int OUT, bool BF16_RELU_OUT>
__launch_bounds__(256, 3)
__global__ void rgcn_layer(const unsigned short* __restrict__ Xb,  // [N][128] bf16
                           const unsigned short* __restrict__ Wt,  // [R][OUT][128] bf16
                           const int4* __restrict__ ebuf,
                           const int* __restrict__ offsets, const int* __restrict__ counts,
                           const float* __restrict__ bias, void* __restrict__ Hout,
                           int nNodes) {
  constexpr int NT = OUT / 64;
  __shared__ __align__(16) unsigned short xs[64][136];    // gathered src rows (stride: 2-way free)
  __shared__ __align__(16) unsigned short ys[OUT][72];    // messages^T [col][edge] (16B-aligned rows)
  __shared__ __align__(16) unsigned short pmat[112][72];  // indicator P [dst_local][edge]
  __shared__ float nrm[64];

  const int t = threadIdx.x;
  const int w = t >> 6;
  const int lane = t & 63;
  const int quad = lane >> 4;
  const int l16 = lane & 15;
  const int nodeBase = blockIdx.x * DSTBLK;
  const int colBase = w * (OUT / 4);

  // entry-zero xs and ys: stale lanes must be finite (0 * NaN = NaN hazard)
  for (int i = t; i < 64 * 136 / 8; i += 256) ((uint4*)xs)[i] = make_uint4(0, 0, 0, 0);
  for (int i = t; i < OUT * 72 / 8; i += 256) ((uint4*)ys)[i] = make_uint4(0, 0, 0, 0);

  f32x4 pacc[MT_P][NT] = {};  // persistent dst-node accumulator (registers)

  for (int r = 0; r < RELS; r++) {
    const int bin = blockIdx.x * RELS + r;
    const int start = offsets[bin];
    const int end = offsets[bin + 1];
    if (start >= end) continue;
    const int realEnd = start + counts[bin];

    // W fragments for this relation, register-resident for the bin
    const unsigned short* Wr = Wt + (size_t)r * OUT * HDIM;
    bf16x8 wf[4][NT];
#pragma unroll
    for (int ks = 0; ks < 4; ks++)
#pragma unroll
      for (int nt = 0; nt < NT; nt++)
        wf[ks][nt] = *(const bf16x8*)(Wr + (size_t)(colBase + nt * 16 + l16) * HDIM + ks * 32 + quad * 8);

    for (int base = start; base < end; base += 64) {
      const int nAct = realEnd - base;
      const int nRows = nAct < 64 ? nAct : 64;  // >= 1 always

      __syncthreads();  // S0: prev chunk's pmat/xs readers done

      // S1: zero pmat; gather xs; edge handlers -> nrm
#pragma unroll
      for (int i = 0; i < 4; i++) {
        int idx = i * 256 + t;
        if (idx < 112 * 72 / 8) ((uint4*)pmat)[idx] = make_uint4(0, 0, 0, 0);
      }
#pragma unroll
      for (int i = 0; i < 4; i++) {
        int idx = i * 256 + t;
        int row = idx >> 4, k8 = idx & 15;
        if (row < nRows) {
          int s = ebuf[base + row].x;
          *(uint4*)&xs[row][k8 * 8] = *(const uint4*)(Xb + (size_t)s * HDIM + k8 * 8);
        }
      }
      int myE = -1, myDloc = -1;
      if ((t & 3) == 0) {
        myE = t >> 2;  // 0..63, spread over all 4 waves
        if (base + myE < realEnd) {
          int4 md = ebuf[base + myE];
          nrm[myE] = __int_as_float(md.z);
          myDloc = md.y - nodeBase;
        } else {
          nrm[myE] = 0.f;
        }
      }
      __syncthreads();  // S2: pmat zeroed, xs + nrm visible

      // S3: build P; main GEMM; scale+cvt+stage ys^T (wave-private columns)
      if (myDloc >= 0) pmat[myDloc][myE] = (unsigned short)0x3F80;  // bf16 1.0
#pragma unroll
      for (int mt = 0; mt < 4; mt++) {
        if (mt * 16 < nRows) {  // wave-uniform
          f32x4 dacc[NT] = {};
#pragma unroll
          for (int ks = 0; ks < 4; ks++) {
            bf16x8 a = *(const bf16x8*)&xs[mt * 16 + l16][ks * 32 + quad * 8];
#pragma unroll
            for (int nt = 0; nt < NT; nt++)
              dacc[nt] = __builtin_amdgcn_mfma_f32_16x16x32_bf16(a, wf[ks][nt], dacc[nt], 0, 0, 0);
          }
          f32x4 nv = *(const f32x4*)&nrm[mt * 16 + quad * 4];
#pragma unroll
          for (int nt = 0; nt < NT; nt++) {
            uint2 pk;
            pk.x = (unsigned)f2bf(dacc[nt][0] * nv[0]) | ((unsigned)f2bf(dacc[nt][1] * nv[1]) << 16);
            pk.y = (unsigned)f2bf(dacc[nt][2] * nv[2]) | ((unsigned)f2bf(dacc[nt][3] * nv[3]) << 16);
            *(uint2*)&ys[colBase + nt * 16 + l16][mt * 16 + quad * 4] = pk;
          }
        }
      }
      __syncthreads();  // S4: pmat built, ys staged

      // S5: aggregation GEMM  Pacc += P @ Y   (k = edges)
#pragma unroll
      for (int ks2 = 0; ks2 < 2; ks2++) {
        if (ks2 * 32 < nRows) {  // wave-uniform
          bf16x8 bf[NT];
#pragma unroll
          for (int nt = 0; nt < NT; nt++)
            bf[nt] = *(const bf16x8*)&ys[colBase + nt * 16 + l16][ks2 * 32 + quad * 8];
#pragma unroll
          for (int mt = 0; mt < MT_P; mt++) {
            bf16x8 a = *(const bf16x8*)&pmat[mt * 16 + l16][ks2 * 32 + quad * 8];
#pragma unroll
            for (int nt = 0; nt < NT; nt++)
              pacc[mt][nt] = __builtin_amdgcn_mfma_f32_16x16x32_bf16(a, bf[nt], pacc[mt][nt], 0, 0, 0);
          }
        }
      }
    }
  }

  // epilogue: each (node, col) owned by exactly one lane -> plain stores
#pragma unroll
  for (int mt = 0; mt < MT_P; mt++) {
#pragma unroll
    for (int reg = 0; reg < 4; reg++) {
      int ld = mt * 16 + quad * 4 + reg;
      int node = nodeBase + ld;
      if (ld < DSTBLK && node < nNodes) {
#pragma unroll
        for (int nt = 0; nt < NT; nt++) {
          int col = colBase + nt * 16 + l16;
          float v = pacc[mt][nt][reg] + bias[col];
          if (BF16_RELU_OUT)
            ((unsigned short*)Hout)[(size_t)node * OUT + col] = f2bf(fmaxf(v, 0.f));
          else
            ((float*)Hout)[(size_t)node * OUT + col] = v;
        }
      }
    }
  }
}

extern "C" void kernel_launch(void* const* d_in, const int* in_sizes, int n_in,
                              void* d_out, int out_size, void* d_ws, size_t ws_size,
                              hipStream_t stream) {
  const int*   src   = (const int*)d_in[1];
  const int*   dst   = (const int*)d_in[2];
  const int*   etype = (const int*)d_in[3];
  const float* norm  = (const float*)d_in[4];
  const float* emb   = (const float*)d_in[5];
  const float* V1    = (const float*)d_in[6];
  const float* comp1 = (const float*)d_in[7];
  const float* bias1 = (const float*)d_in[8];
  const float* V2    = (const float*)d_in[9];
  const float* comp2 = (const float*)d_in[10];
  const float* bias2 = (const float*)d_in[11];
  float* out = (float*)d_out;

  const int N = in_sizes[0];  // 50000
  const int E = in_sizes[1];  // 1000000
  const int H = 128, O = 64;
  const int NB = (N + DSTBLK - 1) / DSTBLK;  // 500
  const int NBINS = NB * RELS;               // 8000
  const int EPAD_MAX = E + NBINS * 16;

  char* ws = (char*)d_ws;
  size_t off = 0;
  auto alloc = [&](size_t bytes) -> void* {
    void* p = ws + off;
    off += (bytes + 255) & ~(size_t)255;
    return p;
  };
  unsigned short* W1t  = (unsigned short*)alloc(sizeof(short) * RELS * H * H);
  unsigned short* W2t  = (unsigned short*)alloc(sizeof(short) * RELS * O * H);
  unsigned short* embh = (unsigned short*)alloc(sizeof(short) * (size_t)N * H);
  unsigned short* h1b  = (unsigned short*)alloc(sizeof(short) * (size_t)N * H);
  int4* ebuf = (int4*)alloc(sizeof(int4) * EPAD_MAX);
  int* counts  = (int*)alloc(sizeof(int) * NBINS);
  int* cursor  = (int*)alloc(sizeof(int) * NBINS);
  int* offsets = (int*)alloc(sizeof(int) * (NBINS + 1));

  hipMemsetAsync(counts, 0, sizeof(int) * NBINS, stream);
  hipMemsetAsync(cursor, 0, sizeof(int) * NBINS, stream);

  cvt_bf16<<<((size_t)N * H / 8 + 255) / 256, 256, 0, stream>>>(emb, embh, N * H / 8);
  compute_w<<<(RELS * H * H + 255) / 256, 256, 0, stream>>>(comp1, V1, W1t, H);
  compute_w<<<(RELS * O * H + 255) / 256, 256, 0, stream>>>(comp2, V2, W2t, O);
  hist_bins<<<1024, 256, 0, stream>>>(dst, etype, E, NBINS, counts);
  scan_offsets<<<1, 256, 0, stream>>>(counts, offsets, NBINS);
  scatter_bins<<<1024, 256, 0, stream>>>(src, dst, etype, norm, E, offsets, cursor, ebuf);

  rgcn_layer<128, true><<<NB, 256, 0, stream>>>(embh, W1t, ebuf, offsets, counts, bias1, (void*)h1b, N);
  rgcn_layer<64, false><<<NB, 256, 0, stream>>>(h1b, W2t, ebuf, offsets, counts, bias2, (void*)out, N);
}